// Round 8
// baseline (1222.256 us; speedup 1.0000x reference)
//
#include <hip/hip_runtime.h>

// LSTMPredictor: 2-layer LSTMCell (H=51), L=1000 steps + 100 autoregressive,
// B=256 chains. One block/batch element (grid=256=#CUs), 768 threads, 3 groups:
//   G0 (tid   0..203): row j of W_hh1 -> gates1 partial (for h1(t+1))
//   G1 (tid 256..459): row j of W_ih2 -> gatesA(t)
//   G2 (tid 512..715): row j of W_hh2 -> gatesB(t)
//
// R8 KEY FIX: the AMDGPU register allocator budgets VGPRs from the MAX of the
// waves-per-EU range; launch_bounds only sets the MIN. Default max (~8/EU)
// => 512/8 = 64-VGPR budget => our 51 weight regs were force-spilled to
// scratch in EVERY prior round (obs 52-56), reloaded through L1 each step.
// amdgpu_waves_per_eu(3,3) pins min=max=3 (block is 12 waves on 4 SIMDs,
// grid=256=#CUs so >1 block/CU never happens anyway) => budget 512/3 ~ 170,
// demand ~102 => weights finally register-resident.
// Body identical to R7: 2 barriers/step hot loop, 3 barriers for the 101
// autoregressive steps; weights pinned via volatile asm "+v" (no remat).

#define B_   256
#define L_   1000
#define H_   51
#define HP   52
#define G4   204
#define GP   208
#define T_   1100

__device__ __forceinline__ float frcp(float v) { return __builtin_amdgcn_rcpf(v); }
__device__ __forceinline__ float sigf(float v) {
    return frcp(1.0f + __expf(-v));
}
__device__ __forceinline__ float tanh_fast(float v) {
    float a = fminf(fmaxf(v, -9.0f), 9.0f);
    float e = __expf(2.0f * a);
    return (e - 1.0f) * frcp(e + 1.0f);
}

// dot of one float4 h-chunk with 4 named weight scalars
#define DOT4(hv, p0, p1, p2, p3) do { \
    a0 = fmaf(p0, (hv).x, a0); a1 = fmaf(p1, (hv).y, a1); \
    a2 = fmaf(p2, (hv).z, a2); a3 = fmaf(p3, (hv).w, a3); } while (0)

#define MATVEC() do { \
    const float4* h4 = (const float4*)hs[s]; \
    float4 hv0 = h4[0], hv1 = h4[1], hv2 = h4[2], hv3 = h4[3]; \
    float4 hv4 = h4[4], hv5 = h4[5], hv6 = h4[6], hv7 = h4[7]; \
    float4 hv8 = h4[8], hv9 = h4[9], hv10 = h4[10], hv11 = h4[11], hv12 = h4[12]; \
    float a0 = bias, a1 = 0.f, a2 = 0.f, a3 = 0.f; \
    DOT4(hv0,  wr0,  wr1,  wr2,  wr3);  DOT4(hv1,  wr4,  wr5,  wr6,  wr7); \
    DOT4(hv2,  wr8,  wr9,  wr10, wr11); DOT4(hv3,  wr12, wr13, wr14, wr15); \
    DOT4(hv4,  wr16, wr17, wr18, wr19); DOT4(hv5,  wr20, wr21, wr22, wr23); \
    DOT4(hv6,  wr24, wr25, wr26, wr27); DOT4(hv7,  wr28, wr29, wr30, wr31); \
    DOT4(hv8,  wr32, wr33, wr34, wr35); DOT4(hv9,  wr36, wr37, wr38, wr39); \
    DOT4(hv10, wr40, wr41, wr42, wr43); DOT4(hv11, wr44, wr45, wr46, wr47); \
    a0 = fmaf(wr48, hv12.x, a0); a1 = fmaf(wr49, hv12.y, a1); a2 = fmaf(wr50, hv12.z, a2); \
    gdst[0] = (a0 + a1) + (a2 + a3); } while (0)

__attribute__((amdgpu_flat_work_group_size(768, 768), amdgpu_waves_per_eu(3, 3)))
__global__ void lstm_pred_kernel(const float* __restrict__ x,
                      const float* __restrict__ W_ih1, const float* __restrict__ W_hh1,
                      const float* __restrict__ b_ih1, const float* __restrict__ b_hh1,
                      const float* __restrict__ W_ih2, const float* __restrict__ W_hh2,
                      const float* __restrict__ b_ih2, const float* __restrict__ b_hh2,
                      const float* __restrict__ W_lin, const float* __restrict__ b_lin,
                      float* __restrict__ out)
{
    __shared__ float xrow[L_];
    __shared__ alignas(16) float gall[3 * GP];  // g1partial | gatesA | gatesB
    __shared__ alignas(16) float hs[2][HP];     // hs[0]=h1, hs[1]=h2
    __shared__ float out_s;

    const int tid = threadIdx.x;
    const int b   = blockIdx.x;
    const int g   = tid >> 8;
    const int j   = tid & 255;
    const bool act = (j < G4);
    const int  s   = (g == 2) ? 1 : 0;

    for (int i = tid; i < L_; i += 768) xrow[i] = x[(size_t)b * L_ + i];
    if (tid < HP) { hs[0][tid] = 0.0f; hs[1][tid] = 0.0f; }

    // ---- one weight row per thread: 51 NAMED scalars ----
    const float* wrow = (g == 0) ? (W_hh1 + j * H_)
                      : (g == 1) ? (W_ih2 + j * H_)
                                 : (W_hh2 + j * H_);
    float bias = 0.0f;
    float wr0=0.f,wr1=0.f,wr2=0.f,wr3=0.f,wr4=0.f,wr5=0.f,wr6=0.f,wr7=0.f,
          wr8=0.f,wr9=0.f,wr10=0.f,wr11=0.f,wr12=0.f,wr13=0.f,wr14=0.f,wr15=0.f,
          wr16=0.f,wr17=0.f,wr18=0.f,wr19=0.f,wr20=0.f,wr21=0.f,wr22=0.f,wr23=0.f,
          wr24=0.f,wr25=0.f,wr26=0.f,wr27=0.f,wr28=0.f,wr29=0.f,wr30=0.f,wr31=0.f,
          wr32=0.f,wr33=0.f,wr34=0.f,wr35=0.f,wr36=0.f,wr37=0.f,wr38=0.f,wr39=0.f,
          wr40=0.f,wr41=0.f,wr42=0.f,wr43=0.f,wr44=0.f,wr45=0.f,wr46=0.f,wr47=0.f,
          wr48=0.f,wr49=0.f,wr50=0.f;
    if (act) {
        if (g == 0)      bias = b_ih1[j] + b_hh1[j];
        else if (g == 1) bias = b_ih2[j] + b_hh2[j];
        wr0 =wrow[0];  wr1 =wrow[1];  wr2 =wrow[2];  wr3 =wrow[3];
        wr4 =wrow[4];  wr5 =wrow[5];  wr6 =wrow[6];  wr7 =wrow[7];
        wr8 =wrow[8];  wr9 =wrow[9];  wr10=wrow[10]; wr11=wrow[11];
        wr12=wrow[12]; wr13=wrow[13]; wr14=wrow[14]; wr15=wrow[15];
        wr16=wrow[16]; wr17=wrow[17]; wr18=wrow[18]; wr19=wrow[19];
        wr20=wrow[20]; wr21=wrow[21]; wr22=wrow[22]; wr23=wrow[23];
        wr24=wrow[24]; wr25=wrow[25]; wr26=wrow[26]; wr27=wrow[27];
        wr28=wrow[28]; wr29=wrow[29]; wr30=wrow[30]; wr31=wrow[31];
        wr32=wrow[32]; wr33=wrow[33]; wr34=wrow[34]; wr35=wrow[35];
        wr36=wrow[36]; wr37=wrow[37]; wr38=wrow[38]; wr39=wrow[39];
        wr40=wrow[40]; wr41=wrow[41]; wr42=wrow[42]; wr43=wrow[43];
        wr44=wrow[44]; wr45=wrow[45]; wr46=wrow[46]; wr47=wrow[47];
        wr48=wrow[48]; wr49=wrow[49]; wr50=wrow[50];
    }
    // PIN: values opaque -> no remat; with the 170-VGPR budget they now FIT.
    asm volatile("" :
        "+v"(wr0),"+v"(wr1),"+v"(wr2),"+v"(wr3),"+v"(wr4),"+v"(wr5),"+v"(wr6),
        "+v"(wr7),"+v"(wr8),"+v"(wr9),"+v"(wr10),"+v"(wr11),"+v"(wr12),"+v"(wr13),
        "+v"(wr14),"+v"(wr15),"+v"(wr16),"+v"(wr17),"+v"(wr18),"+v"(wr19),
        "+v"(wr20),"+v"(wr21),"+v"(wr22),"+v"(wr23),"+v"(wr24),"+v"(wr25));
    asm volatile("" :
        "+v"(wr26),"+v"(wr27),"+v"(wr28),"+v"(wr29),"+v"(wr30),"+v"(wr31),
        "+v"(wr32),"+v"(wr33),"+v"(wr34),"+v"(wr35),"+v"(wr36),"+v"(wr37),
        "+v"(wr38),"+v"(wr39),"+v"(wr40),"+v"(wr41),"+v"(wr42),"+v"(wr43),
        "+v"(wr44),"+v"(wr45),"+v"(wr46),"+v"(wr47),"+v"(wr48),"+v"(wr49),
        "+v"(wr50),"+v"(bias));
    float* gdst = gall + g * GP + j;

    // update-lane extras
    float wi0 = 0.f, wi1 = 0.f, wi2 = 0.f, wi3 = 0.f, wlin = 0.f;
    if (tid < H_) {
        wi0 = W_ih1[tid];
        wi1 = W_ih1[tid + H_];
        wi2 = W_ih1[tid + 2 * H_];
        wi3 = W_ih1[tid + 3 * H_];
    }
    if (tid >= 256 && tid < 256 + H_) wlin = W_lin[tid - 256];
    const float blin = b_lin[0];

    float c1 = 0.f, c2 = 0.f;
    float* outp = out + (size_t)b * T_;

    // ---- prologue: h1(0) (h1(-1)=0 -> gates1 partial = bias1) ----
    if (g == 0 && act) gall[j] = bias;
    __syncthreads();
    if (tid < H_) {
        const float xv = xrow[0];
        float gi = fmaf(wi0, xv, gall[tid]);
        float gf = fmaf(wi1, xv, gall[tid + H_]);
        float gg = fmaf(wi2, xv, gall[tid + 2 * H_]);
        float go = fmaf(wi3, xv, gall[tid + 3 * H_]);
        float ig = sigf(gi), fg = sigf(gf), gv = tanh_fast(gg), og = sigf(go);
        c1 = fmaf(fg, c1, ig * gv);
        hs[0][tid] = og * tanh_fast(c1);
    }
    __syncthreads();

    // ========== hot loop: t = 0..998, 2 barriers/step ==========
    for (int t = 0; t < L_ - 1; ++t) {
        if (act) MATVEC();
        __syncthreads();

        // Phase B1 (wave 4): h2(t) update + output
        if (tid >= 256 && tid < 320) {
            float p = 0.f;
            const int q2 = tid - 256;
            if (q2 < H_) {
                float gi = gall[GP + q2]        + gall[2*GP + q2];
                float gf = gall[GP + q2 +   H_] + gall[2*GP + q2 +   H_];
                float gg = gall[GP + q2 + 2*H_] + gall[2*GP + q2 + 2*H_];
                float go = gall[GP + q2 + 3*H_] + gall[2*GP + q2 + 3*H_];
                float ig = sigf(gi), fg = sigf(gf), gv = tanh_fast(gg), og = sigf(go);
                c2 = fmaf(fg, c2, ig * gv);
                float h2n = og * tanh_fast(c2);
                hs[1][q2] = h2n;
                p = h2n * wlin;
            }
#pragma unroll
            for (int off = 32; off > 0; off >>= 1) p += __shfl_down(p, off);
            if (q2 == 0) outp[t] = p + blin;
        }
        // Phase B2 (wave 0, concurrent): h1(t+1)
        if (tid < H_) {
            const float xv = xrow[t + 1];
            float gi = fmaf(wi0, xv, gall[tid]);
            float gf = fmaf(wi1, xv, gall[tid + H_]);
            float gg = fmaf(wi2, xv, gall[tid + 2 * H_]);
            float go = fmaf(wi3, xv, gall[tid + 3 * H_]);
            float ig = sigf(gi), fg = sigf(gf), gv = tanh_fast(gg), og = sigf(go);
            c1 = fmaf(fg, c1, ig * gv);
            hs[0][tid] = og * tanh_fast(c1);
        }
        __syncthreads();
    }

    // ========== future loop: t = 999..1099 (x <- out_s), 3 barriers ==========
    for (int t = L_ - 1; t < T_; ++t) {
        if (act) MATVEC();
        __syncthreads();

        if (tid >= 256 && tid < 320) {
            float p = 0.f;
            const int q2 = tid - 256;
            if (q2 < H_) {
                float gi = gall[GP + q2]        + gall[2*GP + q2];
                float gf = gall[GP + q2 +   H_] + gall[2*GP + q2 +   H_];
                float gg = gall[GP + q2 + 2*H_] + gall[2*GP + q2 + 2*H_];
                float go = gall[GP + q2 + 3*H_] + gall[2*GP + q2 + 3*H_];
                float ig = sigf(gi), fg = sigf(gf), gv = tanh_fast(gg), og = sigf(go);
                c2 = fmaf(fg, c2, ig * gv);
                float h2n = og * tanh_fast(c2);
                hs[1][q2] = h2n;
                p = h2n * wlin;
            }
#pragma unroll
            for (int off = 32; off > 0; off >>= 1) p += __shfl_down(p, off);
            if (q2 == 0) { float o = p + blin; out_s = o; outp[t] = o; }
        }
        __syncthreads();   // out_s visible to wave 0

        if (tid < H_) {
            const float xv = out_s;
            float gi = fmaf(wi0, xv, gall[tid]);
            float gf = fmaf(wi1, xv, gall[tid + H_]);
            float gg = fmaf(wi2, xv, gall[tid + 2 * H_]);
            float go = fmaf(wi3, xv, gall[tid + 3 * H_]);
            float ig = sigf(gi), fg = sigf(gf), gv = tanh_fast(gg), og = sigf(go);
            c1 = fmaf(fg, c1, ig * gv);
            hs[0][tid] = og * tanh_fast(c1);
        }
        __syncthreads();
    }
}

extern "C" void kernel_launch(void* const* d_in, const int* in_sizes, int n_in,
                              void* d_out, int out_size, void* d_ws, size_t ws_size,
                              hipStream_t stream)
{
    const float* x     = (const float*)d_in[0];
    const float* W_ih1 = (const float*)d_in[1];
    const float* W_hh1 = (const float*)d_in[2];
    const float* b_ih1 = (const float*)d_in[3];
    const float* b_hh1 = (const float*)d_in[4];
    const float* W_ih2 = (const float*)d_in[5];
    const float* W_hh2 = (const float*)d_in[6];
    const float* b_ih2 = (const float*)d_in[7];
    const float* b_hh2 = (const float*)d_in[8];
    const float* W_lin = (const float*)d_in[9];
    const float* b_lin = (const float*)d_in[10];
    float* out = (float*)d_out;

    lstm_pred_kernel<<<B_, 768, 0, stream>>>(x, W_ih1, W_hh1, b_ih1, b_hh1,
                                             W_ih2, W_hh2, b_ih2, b_hh2,
                                             W_lin, b_lin, out);
}

// Round 9
// 1090.918 us; speedup vs baseline: 1.1204x; 1.1204x over previous
//
#include <hip/hip_runtime.h>

// LSTMPredictor: 2-layer LSTMCell (H=51), L=1000 steps + 100 autoregressive,
// B=256 chains. One block/batch element (grid=256=#CUs), 768 threads, 3 groups:
//   G0 (tid   0..203): row j of W_hh1 -> gates1 partial (for h1(t+1))
//   G1 (tid 256..459): row j of W_ih2 -> gatesA(t)
//   G2 (tid 512..715): row j of W_hh2 -> gatesB(t)
//
// R9 KEY FIX: the per-step bottleneck was the h-BROADCAST: 13 ds_read_b128
// per thread = 124 wave-instrs/CU/step, ~12cyc each (uniform b128 still moves
// 1KB into the RF) ~ 1500 cyc/step of LDS pipe — invariant across R3-R8,
// which is why weight residency changes never moved the needle. Now h crosses
// LDS once per wave: lane l does ONE ds_read_b32 of h[l] (unconditional — 
// readlane ignores EXEC, so every lane of every wave must hold valid data),
// then 51 v_readlane broadcasts feed v_fmac directly from SGPRs.
// Weights stay register-resident via R8's recipe (named scalars + asm pin +
// amdgpu_waves_per_eu(3,3): VGPR budget 512/3~170, demand ~70).

#define B_   256
#define L_   1000
#define H_   51
#define HP   64      // padded to wave size: lane l reads hs[l]
#define G4   204
#define GP   208
#define T_   1100

__device__ __forceinline__ float frcp(float v) { return __builtin_amdgcn_rcpf(v); }
__device__ __forceinline__ float sigf(float v) {
    return frcp(1.0f + __expf(-v));
}
__device__ __forceinline__ float tanh_fast(float v) {
    float a = fminf(fmaxf(v, -9.0f), 9.0f);
    float e = __expf(2.0f * a);
    return (e - 1.0f) * frcp(e + 1.0f);
}

// one broadcast-FMA term: h[k] via readlane (SGPR), weight wr##k in VGPR
#define RLF(k, acc) acc = fmaf(__int_as_float(__builtin_amdgcn_readlane(vhi, k)), wr##k, acc)

#define MATVEC() do { \
    float a0 = bias, a1 = 0.f, a2 = 0.f, a3 = 0.f; \
    RLF(0,a0);  RLF(1,a1);  RLF(2,a2);  RLF(3,a3); \
    RLF(4,a0);  RLF(5,a1);  RLF(6,a2);  RLF(7,a3); \
    RLF(8,a0);  RLF(9,a1);  RLF(10,a2); RLF(11,a3); \
    RLF(12,a0); RLF(13,a1); RLF(14,a2); RLF(15,a3); \
    RLF(16,a0); RLF(17,a1); RLF(18,a2); RLF(19,a3); \
    RLF(20,a0); RLF(21,a1); RLF(22,a2); RLF(23,a3); \
    RLF(24,a0); RLF(25,a1); RLF(26,a2); RLF(27,a3); \
    RLF(28,a0); RLF(29,a1); RLF(30,a2); RLF(31,a3); \
    RLF(32,a0); RLF(33,a1); RLF(34,a2); RLF(35,a3); \
    RLF(36,a0); RLF(37,a1); RLF(38,a2); RLF(39,a3); \
    RLF(40,a0); RLF(41,a1); RLF(42,a2); RLF(43,a3); \
    RLF(44,a0); RLF(45,a1); RLF(46,a2); RLF(47,a3); \
    RLF(48,a0); RLF(49,a1); RLF(50,a2); \
    gdst[0] = (a0 + a1) + (a2 + a3); } while (0)

__attribute__((amdgpu_flat_work_group_size(768, 768), amdgpu_waves_per_eu(3, 3)))
__global__ void lstm_pred_kernel(const float* __restrict__ x,
                      const float* __restrict__ W_ih1, const float* __restrict__ W_hh1,
                      const float* __restrict__ b_ih1, const float* __restrict__ b_hh1,
                      const float* __restrict__ W_ih2, const float* __restrict__ W_hh2,
                      const float* __restrict__ b_ih2, const float* __restrict__ b_hh2,
                      const float* __restrict__ W_lin, const float* __restrict__ b_lin,
                      float* __restrict__ out)
{
    __shared__ float xrow[L_];
    __shared__ alignas(16) float gall[3 * GP];  // g1partial | gatesA | gatesB
    __shared__ alignas(16) float hs0[HP];       // h1, padded to 64 (51.. = 0)
    __shared__ alignas(16) float hs1[HP];       // h2
    __shared__ float out_s;

    const int tid  = threadIdx.x;
    const int b    = blockIdx.x;
    const int g    = tid >> 8;
    const int j    = tid & 255;
    const int lane = tid & 63;
    const bool act = (j < G4);

    for (int i = tid; i < L_; i += 768) xrow[i] = x[(size_t)b * L_ + i];
    if (tid < HP) { hs0[tid] = 0.0f; hs1[tid] = 0.0f; }

    // ---- one weight row per thread: 51 NAMED scalars ----
    const float* wrow = (g == 0) ? (W_hh1 + j * H_)
                      : (g == 1) ? (W_ih2 + j * H_)
                                 : (W_hh2 + j * H_);
    float bias = 0.0f;
    float wr0=0.f,wr1=0.f,wr2=0.f,wr3=0.f,wr4=0.f,wr5=0.f,wr6=0.f,wr7=0.f,
          wr8=0.f,wr9=0.f,wr10=0.f,wr11=0.f,wr12=0.f,wr13=0.f,wr14=0.f,wr15=0.f,
          wr16=0.f,wr17=0.f,wr18=0.f,wr19=0.f,wr20=0.f,wr21=0.f,wr22=0.f,wr23=0.f,
          wr24=0.f,wr25=0.f,wr26=0.f,wr27=0.f,wr28=0.f,wr29=0.f,wr30=0.f,wr31=0.f,
          wr32=0.f,wr33=0.f,wr34=0.f,wr35=0.f,wr36=0.f,wr37=0.f,wr38=0.f,wr39=0.f,
          wr40=0.f,wr41=0.f,wr42=0.f,wr43=0.f,wr44=0.f,wr45=0.f,wr46=0.f,wr47=0.f,
          wr48=0.f,wr49=0.f,wr50=0.f;
    if (act) {
        if (g == 0)      bias = b_ih1[j] + b_hh1[j];
        else if (g == 1) bias = b_ih2[j] + b_hh2[j];
        wr0 =wrow[0];  wr1 =wrow[1];  wr2 =wrow[2];  wr3 =wrow[3];
        wr4 =wrow[4];  wr5 =wrow[5];  wr6 =wrow[6];  wr7 =wrow[7];
        wr8 =wrow[8];  wr9 =wrow[9];  wr10=wrow[10]; wr11=wrow[11];
        wr12=wrow[12]; wr13=wrow[13]; wr14=wrow[14]; wr15=wrow[15];
        wr16=wrow[16]; wr17=wrow[17]; wr18=wrow[18]; wr19=wrow[19];
        wr20=wrow[20]; wr21=wrow[21]; wr22=wrow[22]; wr23=wrow[23];
        wr24=wrow[24]; wr25=wrow[25]; wr26=wrow[26]; wr27=wrow[27];
        wr28=wrow[28]; wr29=wrow[29]; wr30=wrow[30]; wr31=wrow[31];
        wr32=wrow[32]; wr33=wrow[33]; wr34=wrow[34]; wr35=wrow[35];
        wr36=wrow[36]; wr37=wrow[37]; wr38=wrow[38]; wr39=wrow[39];
        wr40=wrow[40]; wr41=wrow[41]; wr42=wrow[42]; wr43=wrow[43];
        wr44=wrow[44]; wr45=wrow[45]; wr46=wrow[46]; wr47=wrow[47];
        wr48=wrow[48]; wr49=wrow[49]; wr50=wrow[50];
    }
    // PIN: opaque values -> no remat; fits the 170-VGPR budget from (3,3).
    asm volatile("" :
        "+v"(wr0),"+v"(wr1),"+v"(wr2),"+v"(wr3),"+v"(wr4),"+v"(wr5),"+v"(wr6),
        "+v"(wr7),"+v"(wr8),"+v"(wr9),"+v"(wr10),"+v"(wr11),"+v"(wr12),"+v"(wr13),
        "+v"(wr14),"+v"(wr15),"+v"(wr16),"+v"(wr17),"+v"(wr18),"+v"(wr19),
        "+v"(wr20),"+v"(wr21),"+v"(wr22),"+v"(wr23),"+v"(wr24),"+v"(wr25));
    asm volatile("" :
        "+v"(wr26),"+v"(wr27),"+v"(wr28),"+v"(wr29),"+v"(wr30),"+v"(wr31),
        "+v"(wr32),"+v"(wr33),"+v"(wr34),"+v"(wr35),"+v"(wr36),"+v"(wr37),
        "+v"(wr38),"+v"(wr39),"+v"(wr40),"+v"(wr41),"+v"(wr42),"+v"(wr43),
        "+v"(wr44),"+v"(wr45),"+v"(wr46),"+v"(wr47),"+v"(wr48),"+v"(wr49),
        "+v"(wr50),"+v"(bias));
    float* gdst = gall + g * GP + j;
    const float* hsrc = (g == 2) ? hs1 : hs0;   // wave-uniform h source

    // update-lane extras
    float wi0 = 0.f, wi1 = 0.f, wi2 = 0.f, wi3 = 0.f, wlin = 0.f;
    if (tid < H_) {
        wi0 = W_ih1[tid];
        wi1 = W_ih1[tid + H_];
        wi2 = W_ih1[tid + 2 * H_];
        wi3 = W_ih1[tid + 3 * H_];
    }
    if (tid >= 256 && tid < 256 + H_) wlin = W_lin[tid - 256];
    const float blin = b_lin[0];

    float c1 = 0.f, c2 = 0.f;
    float* outp = out + (size_t)b * T_;

    // ---- prologue: h1(0) (h1(-1)=0 -> gates1 partial = bias1) ----
    if (g == 0 && act) gall[j] = bias;
    __syncthreads();
    if (tid < H_) {
        const float xv = xrow[0];
        float gi = fmaf(wi0, xv, gall[tid]);
        float gf = fmaf(wi1, xv, gall[tid + H_]);
        float gg = fmaf(wi2, xv, gall[tid + 2 * H_]);
        float go = fmaf(wi3, xv, gall[tid + 3 * H_]);
        float ig = sigf(gi), fg = sigf(gf), gv = tanh_fast(gg), og = sigf(go);
        c1 = fmaf(fg, c1, ig * gv);
        hs0[tid] = og * tanh_fast(c1);
    }
    __syncthreads();

    // ========== hot loop: t = 0..998, 2 barriers/step ==========
    for (int t = 0; t < L_ - 1; ++t) {
        // UNCONDITIONAL h-load: every lane of every wave must hold valid h[lane]
        // (readlane ignores EXEC; inactive-lane garbage would poison broadcasts).
        const int vhi = __float_as_int(hsrc[lane]);
        if (act) MATVEC();
        __syncthreads();

        // Phase B1 (wave 4): h2(t) update + output
        if (tid >= 256 && tid < 320) {
            float p = 0.f;
            const int q2 = tid - 256;
            if (q2 < H_) {
                float gi = gall[GP + q2]        + gall[2*GP + q2];
                float gf = gall[GP + q2 +   H_] + gall[2*GP + q2 +   H_];
                float gg = gall[GP + q2 + 2*H_] + gall[2*GP + q2 + 2*H_];
                float go = gall[GP + q2 + 3*H_] + gall[2*GP + q2 + 3*H_];
                float ig = sigf(gi), fg = sigf(gf), gv = tanh_fast(gg), og = sigf(go);
                c2 = fmaf(fg, c2, ig * gv);
                float h2n = og * tanh_fast(c2);
                hs1[q2] = h2n;
                p = h2n * wlin;
            }
#pragma unroll
            for (int off = 32; off > 0; off >>= 1) p += __shfl_down(p, off);
            if (q2 == 0) outp[t] = p + blin;
        }
        // Phase B2 (wave 0, concurrent): h1(t+1)
        if (tid < H_) {
            const float xv = xrow[t + 1];
            float gi = fmaf(wi0, xv, gall[tid]);
            float gf = fmaf(wi1, xv, gall[tid + H_]);
            float gg = fmaf(wi2, xv, gall[tid + 2 * H_]);
            float go = fmaf(wi3, xv, gall[tid + 3 * H_]);
            float ig = sigf(gi), fg = sigf(gf), gv = tanh_fast(gg), og = sigf(go);
            c1 = fmaf(fg, c1, ig * gv);
            hs0[tid] = og * tanh_fast(c1);
        }
        __syncthreads();
    }

    // ========== future loop: t = 999..1099 (x <- out_s), 3 barriers ==========
    for (int t = L_ - 1; t < T_; ++t) {
        const int vhi = __float_as_int(hsrc[lane]);
        if (act) MATVEC();
        __syncthreads();

        if (tid >= 256 && tid < 320) {
            float p = 0.f;
            const int q2 = tid - 256;
            if (q2 < H_) {
                float gi = gall[GP + q2]        + gall[2*GP + q2];
                float gf = gall[GP + q2 +   H_] + gall[2*GP + q2 +   H_];
                float gg = gall[GP + q2 + 2*H_] + gall[2*GP + q2 + 2*H_];
                float go = gall[GP + q2 + 3*H_] + gall[2*GP + q2 + 3*H_];
                float ig = sigf(gi), fg = sigf(gf), gv = tanh_fast(gg), og = sigf(go);
                c2 = fmaf(fg, c2, ig * gv);
                float h2n = og * tanh_fast(c2);
                hs1[q2] = h2n;
                p = h2n * wlin;
            }
#pragma unroll
            for (int off = 32; off > 0; off >>= 1) p += __shfl_down(p, off);
            if (q2 == 0) { float o = p + blin; out_s = o; outp[t] = o; }
        }
        __syncthreads();   // out_s visible to wave 0

        if (tid < H_) {
            const float xv = out_s;
            float gi = fmaf(wi0, xv, gall[tid]);
            float gf = fmaf(wi1, xv, gall[tid + H_]);
            float gg = fmaf(wi2, xv, gall[tid + 2 * H_]);
            float go = fmaf(wi3, xv, gall[tid + 3 * H_]);
            float ig = sigf(gi), fg = sigf(gf), gv = tanh_fast(gg), og = sigf(go);
            c1 = fmaf(fg, c1, ig * gv);
            hs0[tid] = og * tanh_fast(c1);
        }
        __syncthreads();
    }
}

extern "C" void kernel_launch(void* const* d_in, const int* in_sizes, int n_in,
                              void* d_out, int out_size, void* d_ws, size_t ws_size,
                              hipStream_t stream)
{
    const float* x     = (const float*)d_in[0];
    const float* W_ih1 = (const float*)d_in[1];
    const float* W_hh1 = (const float*)d_in[2];
    const float* b_ih1 = (const float*)d_in[3];
    const float* b_hh1 = (const float*)d_in[4];
    const float* W_ih2 = (const float*)d_in[5];
    const float* W_hh2 = (const float*)d_in[6];
    const float* b_ih2 = (const float*)d_in[7];
    const float* b_hh2 = (const float*)d_in[8];
    const float* W_lin = (const float*)d_in[9];
    const float* b_lin = (const float*)d_in[10];
    float* out = (float*)d_out;

    lstm_pred_kernel<<<B_, 768, 0, stream>>>(x, W_ih1, W_hh1, b_ih1, b_hh1,
                                             W_ih2, W_hh2, b_ih2, b_hh2,
                                             W_lin, b_lin, out);
}